// Round 6
// baseline (118.004 us; speedup 1.0000x reference)
//
#include <hip/hip_runtime.h>

// Problem constants
#define NPX    2097152                // 4*512*1024 pixels per head
#define NPX4   (NPX/4)
#define CH_STR 8192                   // 64*128
#define IMG_STR 155648                // 19*8192

// Workspace: ctl region after (unused) 16MB prob area.
#define OFF_CTL   (2ull*NPX*4)
// ctl layout in u32 units
#define CTL_CNT1    0                   // 64 buckets x 32-u32 stride (completion lvl1)
#define CTL_CNT2    2048                // level-2 completion counter (own cacheline)
#define CTL_GHIST   4096                // u[4096] slow-path histogram (cold)
#define CTL_PPSUM   8192                // f[2*2048*4] per-wave partials
#define CTL_PPCNT   24576               // u[2*2048*4]
#define CTL_BPS     40960               // f[512*2]
#define CTL_BPC     41984               // u[512*2]

#define GRID_P1    4608u               // 4096 OHEM rows + 512 BCE = 72 * 64

// Device-coherent (cross-XCD) single-access ops: relaxed AGENT atomics compile
// to sc1 global ops (write-through / L2-bypass) — no L2 flush (R1 lesson).
__device__ __forceinline__ void st_dev_f(float* p, float v) {
    __hip_atomic_store(p, v, __ATOMIC_RELAXED, __HIP_MEMORY_SCOPE_AGENT);
}
__device__ __forceinline__ void st_dev_u(unsigned* p, unsigned v) {
    __hip_atomic_store(p, v, __ATOMIC_RELAXED, __HIP_MEMORY_SCOPE_AGENT);
}
__device__ __forceinline__ float ld_dev_f(const float* p) {
    return __hip_atomic_load((float*)p, __ATOMIC_RELAXED, __HIP_MEMORY_SCOPE_AGENT);
}
__device__ __forceinline__ unsigned ld_dev_u(const unsigned* p) {
    return __hip_atomic_load((unsigned*)p, __ATOMIC_RELAXED, __HIP_MEMORY_SCOPE_AGENT);
}

// ---------------------------------------------------------------------------
// COLD slow path (C < 100000 for a head — never taken on this input, kept for
// correctness): single-block exact 3-level radix select over RECOMPUTED
// mask_prob values (bit-identical math to the hot path), then masked reduce.
// ---------------------------------------------------------------------------
__device__ __attribute__((noinline)) void slow_head(
    int tid, const float* __restrict__ pred, const int* __restrict__ seg,
    unsigned* __restrict__ ghist, float2* erow,
    float* smf, unsigned* smu)
{
    int xb = tid << 2;
    float fx0 = (float)xb * (127.0f / 1023.0f);
    int X = min((int)fx0, 126);
    float wA[4], wB[4], wC[4];
#pragma unroll
    for (int dx = 0; dx < 4; ++dx) {
        float fx = (float)(xb + dx) * (127.0f / 1023.0f);
        int x0 = min((int)fx, 127);
        float wx = fx - (float)x0;
        bool sm = (x0 == X);
        wA[dx] = sm ? (1.0f - wx) : 0.0f;
        wB[dx] = sm ? wx : (1.0f - wx);
        wC[dx] = sm ? 0.0f : wx;
    }

    for (int lvl = 0; lvl < 4; ++lvl) {          // 3 select levels + 1 reduce pass
        if (lvl < 3) {
            for (int i = tid; i < 4096; i += 256) ghist[i] = 0u;
        }
        __syncthreads();
        unsigned pre = (lvl == 0) ? 0u : smu[0];
        float th = smf[0];
        float fs = 0.f; unsigned ic = 0;

        for (int task = 0; task < 2048; ++task) {
            int b = task >> 9, y = task & 511;
            float fy = (float)y * (63.0f / 511.0f);
            int y0 = min((int)fy, 63);
            int y1 = min(y0 + 1, 63);
            float wy = fy - (float)y0;
            const float* r0 = pred + (size_t)b * IMG_STR + y0 * 128;
            const float* r1 = pred + (size_t)b * IMG_STR + y1 * 128;
            for (int i = tid; i < 2432; i += 256) {
                int c = i >> 7, x = i & 127;
                float v0 = r0[c * CH_STR + x];
                float v1 = r1[c * CH_STR + x];
                float e = fmaf(wy, v1 - v0, v0);
                erow[c * 128 + x].x = e;
                if (x > 0)    erow[c * 128 + x - 1].y = e;
                if (x == 127) erow[c * 128 + 127].y = e;
            }
            __syncthreads();

            int P = task * 1024 + xb;
            int4 t4 = *(const int4*)(seg + P);
            int t[4] = {t4.x, t4.y, t4.z, t4.w};

            float acc[4] = {0.f, 0.f, 0.f, 0.f};
            for (int c = 0; c < 19; ++c) {
                float2 eA = erow[c * 128 + X];
                float2 eB = erow[c * 128 + X + 1];
#pragma unroll
                for (int dx = 0; dx < 4; ++dx) {
                    float l = fmaf(eA.x, wA[dx], fmaf(eA.y, wB[dx], eB.y * wC[dx]));
                    acc[dx] += __expf(l);
                }
            }
#pragma unroll
            for (int dx = 0; dx < 4; ++dx) {
                bool valid = (t[dx] != 255);
                int tc = valid ? t[dx] : 0;
                float2 eA = erow[tc * 128 + X];
                float2 eB = erow[tc * 128 + X + 1];
                float lt = fmaf(eA.x, wA[dx], fmaf(eA.y, wB[dx], eB.y * wC[dx]));
                float ls = __logf(acc[dx]);
                float n  = ls - lt;
                float p  = fminf(__expf(-n), 1.0f);
                float pr = valid ? p : 1.0f;        // mask_prob (invalid -> 1.0)
                if (lvl < 3) {
                    unsigned bv = __float_as_uint(pr);
                    if (lvl == 0)      atomicAdd(&ghist[bv >> 18], 1u);
                    else if (lvl == 1) { if ((bv >> 18) == pre) atomicAdd(&ghist[(bv >> 6) & 0xFFFu], 1u); }
                    else               { if ((bv >> 6) == pre) atomicAdd(&ghist[bv & 63u], 1u); }
                } else {
                    if (valid && p <= th) { fs -= __logf(p); ic++; }
                }
            }
            __syncthreads();                       // before next row's erow rewrite
        }

        if (lvl < 3) {
            if (tid == 0) {                        // serial scan (cold path)
                int bins = (lvl == 2) ? 64 : 4096;
                unsigned kr = (lvl == 0) ? 100000u : smu[1];
                unsigned acc = 0;
                for (int idx = 0; idx < bins; ++idx) {
                    unsigned c = ghist[idx];
                    if (acc < kr && kr <= acc + c) {
                        if (lvl == 0)      { smu[0] = (unsigned)idx; smu[1] = kr - acc; }
                        else if (lvl == 1) { smu[0] = (pre << 12) | (unsigned)idx; smu[1] = kr - acc; }
                        else {
                            unsigned bitsv = (pre << 6) | (unsigned)idx;
                            smf[0] = fmaxf(0.7f, __uint_as_float(bitsv));
                        }
                        break;
                    }
                    acc += c;
                }
            }
            __syncthreads();
        } else {
            for (int o = 32; o; o >>= 1) {
                fs += __shfl_down(fs, o, 64);
                ic += (unsigned)__shfl_down((int)ic, o, 64);
            }
            int wave = tid >> 6, lane = tid & 63;
            if (lane == 0) { smf[4 + wave] = fs; smu[4 + wave] = ic; }
            __syncthreads();
            if (tid == 0) {
                smf[1] = smf[4] + smf[5] + smf[6] + smf[7];
                smu[2] = smu[4] + smu[5] + smu[6] + smu[7];
            }
            __syncthreads();
        }
    }
}

// ---------------------------------------------------------------------------
// Single fused kernel, ONE ROW PER BLOCK (the measured-best R0 shape).
// Blocks [0,4096) = OHEM: stage the 2 input rows as float4 (3 rounds),
// build erow via shfl (harness-verified bit-identical), px loop verbatim,
// per-WAVE partials stored with sc1 (no second barrier; decide re-sums each
// quad in the exact ((w0+w1)+w2)+w3 order => S/C bit-identical).
// Blocks [4096,4608) = boundary BCE (unchanged). Hierarchical completion;
// last block: decide -> fast combine (verbatim) or cold slow path.
// ---------------------------------------------------------------------------
__global__ __launch_bounds__(256) void fused_all(
    const float* __restrict__ mp, const float* __restrict__ cp,
    const float* __restrict__ bp, const int* __restrict__ seg,
    const float* __restrict__ bg,
    float* __restrict__ ppsum, unsigned* __restrict__ ppcnt,
    float* __restrict__ bps, unsigned* __restrict__ bpc,
    unsigned* __restrict__ cnt1, unsigned* __restrict__ cnt2,
    unsigned* __restrict__ ghist,
    float* __restrict__ out)
{
    __shared__ float2 erow[19 * 128];          // 19.5 KB (reused as finisher scratch)
    __shared__ float rf[4]; __shared__ unsigned ru[4];
    __shared__ float rf2[4]; __shared__ unsigned ru2[4];
    __shared__ unsigned amLast;
    __shared__ float Pb[4], Nb[4]; __shared__ unsigned PCb[4], NCb[4];
    __shared__ float smf[8]; __shared__ unsigned smu[8];
    int bk = blockIdx.x;
    int tid = threadIdx.x;

    if (bk < 4096) {
        // Chunked XCD swizzle: XCD (bk&7) gets one (head,b) image slice
        // (512 consecutive rows): v = (bk&7)*512 + bk>>3  (bijection).
        int v = ((bk & 7) << 9) | (bk >> 3);
        int head = v >> 11;
        int task = v & 2047;                   // b*512 + y
        int b = task >> 9;
        int y = task & 511;
        const float* pred = head ? cp : mp;

        float fy = (float)y * (63.0f / 511.0f);
        int y0 = min((int)fy, 63);
        int y1 = min(y0 + 1, 63);
        float wy = fy - (float)y0;

        // Prefetch seg early — hides under staging + barrier.
        int xb = tid << 2;
        int P = task * 1024 + xb;              // per-head pixel index
        int4 t4 = *(const int4*)(seg + P);
        int t[4] = {t4.x, t4.y, t4.z, t4.w};

        // Stage + vertical lerp + erow build (float4 loads, shfl neighbor).
        const float* r0 = pred + (size_t)b * IMG_STR + y0 * 128;
        const float* r1 = pred + (size_t)b * IMG_STR + y1 * 128;
#pragma unroll
        for (int sr = 0; sr < 3; ++sr) {
            int s = tid + (sr << 8);           // 608 float4 slots
            float4 cu = make_float4(0.f, 0.f, 0.f, 0.f);
            float4 nx = make_float4(0.f, 0.f, 0.f, 0.f);
            int c = s >> 5, x4 = (s & 31) << 2;
            if (s < 608) {
                cu = *(const float4*)(r0 + c * CH_STR + x4);
                nx = *(const float4*)(r1 + c * CH_STR + x4);
            }
            float e0 = fmaf(wy, nx.x - cu.x, cu.x);
            float e1 = fmaf(wy, nx.y - cu.y, cu.y);
            float e2 = fmaf(wy, nx.z - cu.z, cu.z);
            float e3 = fmaf(wy, nx.w - cu.w, cu.w);
            float en = __shfl_down(e0, 1, 64);   // next slot's e0 (same wave)
            if (s < 608) {
                float last = ((s & 31) == 31) ? e3 : en;  // channel edge pad
                float4 w0 = make_float4(e0, e1, e1, e2);
                float4 w1 = make_float4(e2, e3, e3, last);
                *(float4*)(&erow[c * 128 + x4])     = w0;
                *(float4*)(&erow[c * 128 + x4 + 2]) = w1;
            }
        }
        __syncthreads();

        // Per-thread horizontal taps/weights.
        float fx0 = (float)xb * (127.0f / 1023.0f);
        int X = min((int)fx0, 126);                  // taps e[X], e[X+1], e[X+2]
        float wA[4], wB[4], wC[4];
#pragma unroll
        for (int dx = 0; dx < 4; ++dx) {
            float fx = (float)(xb + dx) * (127.0f / 1023.0f);
            int x0 = min((int)fx, 127);
            float wx = fx - (float)x0;
            bool sm = (x0 == X);
            wA[dx] = sm ? (1.0f - wx) : 0.0f;        // weight on e[X]   (eA.x)
            wB[dx] = sm ? wx : (1.0f - wx);          // weight on e[X+1] (eA.y)
            wC[dx] = sm ? 0.0f : wx;                 // weight on e[X+2] (eB.y)
        }

        // ---- px loop: verbatim hot math ----
        float acc[4] = {0.f, 0.f, 0.f, 0.f};
        for (int c = 0; c < 19; ++c) {
            float2 eA = erow[c * 128 + X];           // (e[X],   e[X+1])
            float2 eB = erow[c * 128 + X + 1];       // (e[X+1], e[X+2])
#pragma unroll
            for (int dx = 0; dx < 4; ++dx) {
                float l = fmaf(eA.x, wA[dx], fmaf(eA.y, wB[dx], eB.y * wC[dx]));
                acc[dx] += __expf(l);
            }
        }

        float fs = 0.f; unsigned ic = 0;
#pragma unroll
        for (int dx = 0; dx < 4; ++dx) {
            bool valid = (t[dx] != 255);
            int tc = valid ? t[dx] : 0;
            float2 eA = erow[tc * 128 + X];
            float2 eB = erow[tc * 128 + X + 1];
            float lt = fmaf(eA.x, wA[dx], fmaf(eA.y, wB[dx], eB.y * wC[dx]));  // bit-identical
            float ls = __logf(acc[dx]);
            float n  = ls - lt;                      // nll at target
            float p  = fminf(__expf(-n), 1.0f);
            if (valid && p <= 0.7f) { fs += n; ic++; }
        }

        // Per-wave partial (sc1), drained before the completion barrier.
        for (int o = 32; o; o >>= 1) {
            fs += __shfl_down(fs, o, 64);
            ic += (unsigned)__shfl_down((int)ic, o, 64);
        }
        int wave = tid >> 6, lane = tid & 63;
        if (lane == 0) {
            int base = (head * 2048 + task) << 2;
            st_dev_f(&ppsum[base + wave], fs);
            st_dev_u(&ppcnt[base + wave], ic);
            asm volatile("s_waitcnt vmcnt(0)" ::: "memory");
        }
    } else {
        // -------- boundary BCE --------
        int bb = bk - 4096;                   // [0,512)
        int b  = bb >> 7;                     // 128 blocks per sample
        int blk = bb & 127;
        float psum = 0.f, nsum = 0.f; unsigned pc = 0, nc = 0;

        for (int g = blk * 256 + tid; g < 131072; g += 128 * 256) {
            int P = g << 2;
            int y = P >> 10, xb = P & 1023;

            float fy = (float)y * (63.0f / 511.0f);
            int y0 = min((int)fy, 63);
            int y1 = min(y0 + 1, 63);
            float wy = fy - (float)y0;

            const float* r0 = bp + b * 8192 + y0 * 128;
            const float* r1 = bp + b * 8192 + y1 * 128;
            float fx0 = (float)xb * (127.0f / 1023.0f);
            int X  = min((int)fx0, 126);
            int X2 = min(X + 2, 127);
            float c0 = r0[X], c1 = r0[X + 1], c2 = r0[X2];
            float d0 = r1[X], d1 = r1[X + 1], d2 = r1[X2];
            float e0 = fmaf(wy, d0 - c0, c0);
            float e1 = fmaf(wy, d1 - c1, c1);
            float e2 = fmaf(wy, d2 - c2, c2);

            float4 t4 = *(const float4*)(bg + (size_t)b * 524288 + P);
            float tv[4] = {t4.x, t4.y, t4.z, t4.w};

#pragma unroll
            for (int dx = 0; dx < 4; ++dx) {
                float fx = (float)(xb + dx) * (127.0f / 1023.0f);
                int x0 = min((int)fx, 127);
                int x1 = min(x0 + 1, 127);
                float wx = fx - (float)x0;
                float a0 = (x0 == X)     ? e0 : e1;
                float a1 = (x1 == X + 1) ? e1 : e2;
                float p  = fmaf(wx, a1 - a0, a0);
                bool isp = (tv[dx] == 1.0f);
                bool isn = (tv[dx] == 0.0f);
                float q = isp ? p : 1.0f - p;
                float l = fmaxf(__logf(q), -100.0f);
                if (isp) { pc++; psum -= l; }
                if (isn) { nc++; nsum -= l; }
            }
        }
        for (int o = 32; o; o >>= 1) {
            psum += __shfl_down(psum, o, 64);
            nsum += __shfl_down(nsum, o, 64);
            pc   += (unsigned)__shfl_down((int)pc, o, 64);
            nc   += (unsigned)__shfl_down((int)nc, o, 64);
        }
        int wave = tid >> 6, lane = tid & 63;
        if (lane == 0) { rf[wave] = psum; rf2[wave] = nsum; ru[wave] = pc; ru2[wave] = nc; }
        __syncthreads();
        if (tid == 0) {
            st_dev_f(&bps[2 * bb],     rf[0] + rf[1] + rf[2] + rf[3]);
            st_dev_f(&bps[2 * bb + 1], rf2[0] + rf2[1] + rf2[2] + rf2[3]);
            st_dev_u(&bpc[2 * bb],     ru[0] + ru[1] + ru[2] + ru[3]);
            st_dev_u(&bpc[2 * bb + 1], ru2[0] + ru2[1] + ru2[2] + ru2[3]);
        }
    }

    // ---------------- last-block finisher ----------------
    // Barrier ensures every wave's lane0 executed its vmcnt drain (OHEM) or
    // tid0 stored+drains below (BCE). Hierarchical completion: 72 blocks per
    // level-1 bucket; winners bump level-2; lvl2 old==63 => last block.
    __syncthreads();
    if (tid == 0) {
        asm volatile("s_waitcnt vmcnt(0)" ::: "memory");
        unsigned last = 0u;
        unsigned o1 = __hip_atomic_fetch_add(&cnt1[(bk & 63) << 5], 1u,
                                             __ATOMIC_RELAXED, __HIP_MEMORY_SCOPE_AGENT);
        if (o1 == 71u) {
            unsigned o2 = __hip_atomic_fetch_add(cnt2, 1u,
                                                 __ATOMIC_RELAXED, __HIP_MEMORY_SCOPE_AGENT);
            last = (o2 == 63u) ? 1u : 0u;
        }
        amLast = last;
    }
    __syncthreads();
    if (!amLast) return;

    // ---- decide: re-sum each task's wave-quad in the exact ((w0+w1)+w2)+w3
    // order (== old rf[0]+rf[1]+rf[2]+rf[3]), then the original tid-strided
    // accumulation => S/C bit-identical to all previous rounds.
    float s0 = 0.f, s1 = 0.f; unsigned c0 = 0u, c1 = 0u;
    for (int i = tid; i < 2048; i += 256) {
        {
            const float* ps = &ppsum[i << 2];
            const unsigned* pq = &ppcnt[i << 2];
            s0 += ld_dev_f(&ps[0]) + ld_dev_f(&ps[1]) + ld_dev_f(&ps[2]) + ld_dev_f(&ps[3]);
            c0 += ld_dev_u(&pq[0]) + ld_dev_u(&pq[1]) + ld_dev_u(&pq[2]) + ld_dev_u(&pq[3]);
        }
        {
            const float* ps = &ppsum[(2048 + i) << 2];
            const unsigned* pq = &ppcnt[(2048 + i) << 2];
            s1 += ld_dev_f(&ps[0]) + ld_dev_f(&ps[1]) + ld_dev_f(&ps[2]) + ld_dev_f(&ps[3]);
            c1 += ld_dev_u(&pq[0]) + ld_dev_u(&pq[1]) + ld_dev_u(&pq[2]) + ld_dev_u(&pq[3]);
        }
    }
    for (int o = 32; o; o >>= 1) {
        s0 += __shfl_down(s0, o, 64); s1 += __shfl_down(s1, o, 64);
        c0 += (unsigned)__shfl_down((int)c0, o, 64);
        c1 += (unsigned)__shfl_down((int)c1, o, 64);
    }
    int wv = tid >> 6, ln = tid & 63;
    if (ln == 0) { rf[wv] = s0; rf2[wv] = s1; ru[wv] = c0; ru2[wv] = c1; }
    __syncthreads();
    float S0 = rf[0] + rf[1] + rf[2] + rf[3];
    float S1 = rf2[0] + rf2[1] + rf2[2] + rf2[3];
    unsigned C0 = ru[0] + ru[1] + ru[2] + ru[3];
    unsigned C1 = ru2[0] + ru2[1] + ru2[2] + ru2[3];
    bool done0 = (C0 >= 100000u), done1 = (C1 >= 100000u);

    // Head losses: fast heads verbatim; undone heads via cold recompute.
    float hl0, hl1;
    if (done0) {
        hl0 = S0 / fmaxf((float)C0, 1.f);
    } else {
        slow_head(tid, mp, seg, ghist, erow, smf, smu);
        hl0 = smf[1] / fmaxf((float)smu[2], 1.f);
    }
    if (done1) {
        hl1 = S1 / fmaxf((float)C1, 1.f);
    } else {
        slow_head(tid, cp, seg, ghist, erow, smf, smu);
        hl1 = smf[1] / fmaxf((float)smu[2], 1.f);
    }
    float hls = hl0 + hl1;

    // boundary combine — same tree algorithm/order as before (absmax-proven)
    {
        float*    lf = (float*)erow;
        unsigned* lu = (unsigned*)erow + 256;
        for (int b = 0; b < 4; ++b) {
            float ps = 0.f, ns = 0.f; unsigned p_c = 0, n_c = 0;
            if (tid < 128) {
                int jj = b * 128 + tid;
                ps  = ld_dev_f(&bps[2 * jj]); ns  = ld_dev_f(&bps[2 * jj + 1]);
                p_c = ld_dev_u(&bpc[2 * jj]); n_c = ld_dev_u(&bpc[2 * jj + 1]);
            }
            lf[tid] = ps; lu[tid] = p_c; __syncthreads();
            for (int o = 128; o; o >>= 1) {
                if (tid < o) { lf[tid] += lf[tid + o]; lu[tid] += lu[tid + o]; }
                __syncthreads();
            }
            if (tid == 0) { Pb[b] = lf[0]; PCb[b] = lu[0]; }
            __syncthreads();
            lf[tid] = ns; lu[tid] = n_c; __syncthreads();
            for (int o = 128; o; o >>= 1) {
                if (tid < o) { lf[tid] += lf[tid + o]; lu[tid] += lu[tid + o]; }
                __syncthreads();
            }
            if (tid == 0) { Nb[b] = lf[0]; NCb[b] = lu[0]; }
            __syncthreads();
        }
        if (tid == 0) {
            float bt = 0.f;
            for (int b = 0; b < 4; ++b) {
                float pos = (float)PCb[b], neg = (float)NCb[b];
                float val = fmaxf(pos + neg, 1.f);
                bt += (neg / val) * Pb[b] + (pos / val) * Nb[b];
            }
            out[0] = hls + bt / 2097152.0f;
        }
    }
}

extern "C" void kernel_launch(void* const* d_in, const int* in_sizes, int n_in,
                              void* d_out, int out_size, void* d_ws, size_t ws_size,
                              hipStream_t stream)
{
    const float* mp  = (const float*)d_in[0];
    const float* cp  = (const float*)d_in[1];
    const float* bp  = (const float*)d_in[2];
    const int*   seg = (const int*)d_in[3];
    const float* bg  = (const float*)d_in[4];
    float* out = (float*)d_out;

    char* ws = (char*)d_ws;
    unsigned* ctl    = (unsigned*)(ws + OFF_CTL);
    unsigned* cnt1   = ctl + CTL_CNT1;
    unsigned* cnt2   = ctl + CTL_CNT2;
    unsigned* ghist  = ctl + CTL_GHIST;
    float*    ppsum  = (float*)(ctl + CTL_PPSUM);
    unsigned* ppcnt  = ctl + CTL_PPCNT;
    float*    bps    = (float*)(ctl + CTL_BPS);
    unsigned* bpc    = ctl + CTL_BPC;

    // Zero completion counters only (ghist is zeroed by the slow path itself).
    hipMemsetAsync(ws + OFF_CTL, 0, 2052ull * 4, stream);

    fused_all<<<dim3(GRID_P1), 256, 0, stream>>>(mp, cp, bp, seg, bg,
                                                 ppsum, ppcnt, bps, bpc,
                                                 cnt1, cnt2, ghist, out);
}

// Round 7
// 110.280 us; speedup vs baseline: 1.0700x; 1.0700x over previous
//
#include <hip/hip_runtime.h>

// Problem constants
#define NPX    2097152                // 4*512*1024 pixels per head
#define NPX4   (NPX/4)
#define CH_STR 8192                   // 64*128
#define IMG_STR 155648                // 19*8192

// Workspace: ctl region after (unused) 16MB prob area.
#define OFF_CTL   (2ull*NPX*4)
// ctl layout in u32 units
#define CTL_CNT1    0                   // 64 buckets x 32-u32 stride (completion lvl1)
#define CTL_CNT2    2048                // level-2 completion counter (own cacheline)
#define CTL_GHIST   4096                // u[4096] slow-path histogram (cold)
#define CTL_PPSUM   8192                // f[2*2048]
#define CTL_PPCNT   12288               // u[2*2048]
#define CTL_BPS     16384               // f[512*2]
#define CTL_BPC     17408               // u[512*2]

#define GRID_P1    4608u               // 4096 OHEM rows + 512 BCE = 72 * 64

// Padded LDS pair index: 1 dummy pair per 8 -> write-side banks stride ~9
// (coprime with 32) instead of 8 (16-deep hotspot, the R6 regression).
#define ESTR 144                       // channel stride in float2 pairs

// Device-coherent (cross-XCD) single-access ops: relaxed AGENT atomics compile
// to sc1 global ops (write-through / L2-bypass) — no L2 flush (R1 lesson).
__device__ __forceinline__ void st_dev_f(float* p, float v) {
    __hip_atomic_store(p, v, __ATOMIC_RELAXED, __HIP_MEMORY_SCOPE_AGENT);
}
__device__ __forceinline__ void st_dev_u(unsigned* p, unsigned v) {
    __hip_atomic_store(p, v, __ATOMIC_RELAXED, __HIP_MEMORY_SCOPE_AGENT);
}
__device__ __forceinline__ float ld_dev_f(const float* p) {
    return __hip_atomic_load((float*)p, __ATOMIC_RELAXED, __HIP_MEMORY_SCOPE_AGENT);
}
__device__ __forceinline__ unsigned ld_dev_u(const unsigned* p) {
    return __hip_atomic_load((unsigned*)p, __ATOMIC_RELAXED, __HIP_MEMORY_SCOPE_AGENT);
}

// ---------------------------------------------------------------------------
// COLD slow path (C < 100000 for a head — never taken on this input, kept for
// correctness): single-block exact 3-level radix select over RECOMPUTED
// mask_prob values (bit-identical math to the hot path), then masked reduce.
// Uses its own (unpadded) indexing of the shared erow buffer — internally
// consistent; buffer is larger than it needs.
// ---------------------------------------------------------------------------
__device__ __attribute__((noinline)) void slow_head(
    int tid, const float* __restrict__ pred, const int* __restrict__ seg,
    unsigned* __restrict__ ghist, float2* erow,
    float* smf, unsigned* smu)
{
    int xb = tid << 2;
    float fx0 = (float)xb * (127.0f / 1023.0f);
    int X = min((int)fx0, 126);
    float wA[4], wB[4], wC[4];
#pragma unroll
    for (int dx = 0; dx < 4; ++dx) {
        float fx = (float)(xb + dx) * (127.0f / 1023.0f);
        int x0 = min((int)fx, 127);
        float wx = fx - (float)x0;
        bool sm = (x0 == X);
        wA[dx] = sm ? (1.0f - wx) : 0.0f;
        wB[dx] = sm ? wx : (1.0f - wx);
        wC[dx] = sm ? 0.0f : wx;
    }

    for (int lvl = 0; lvl < 4; ++lvl) {          // 3 select levels + 1 reduce pass
        if (lvl < 3) {
            for (int i = tid; i < 4096; i += 256) ghist[i] = 0u;
        }
        __syncthreads();
        unsigned pre = (lvl == 0) ? 0u : smu[0];
        float th = smf[0];
        float fs = 0.f; unsigned ic = 0;

        for (int task = 0; task < 2048; ++task) {
            int b = task >> 9, y = task & 511;
            float fy = (float)y * (63.0f / 511.0f);
            int y0 = min((int)fy, 63);
            int y1 = min(y0 + 1, 63);
            float wy = fy - (float)y0;
            const float* r0 = pred + (size_t)b * IMG_STR + y0 * 128;
            const float* r1 = pred + (size_t)b * IMG_STR + y1 * 128;
            for (int i = tid; i < 2432; i += 256) {
                int c = i >> 7, x = i & 127;
                float v0 = r0[c * CH_STR + x];
                float v1 = r1[c * CH_STR + x];
                float e = fmaf(wy, v1 - v0, v0);
                erow[c * 128 + x].x = e;
                if (x > 0)    erow[c * 128 + x - 1].y = e;
                if (x == 127) erow[c * 128 + 127].y = e;
            }
            __syncthreads();

            int P = task * 1024 + xb;
            int4 t4 = *(const int4*)(seg + P);
            int t[4] = {t4.x, t4.y, t4.z, t4.w};

            float acc[4] = {0.f, 0.f, 0.f, 0.f};
            for (int c = 0; c < 19; ++c) {
                float2 eA = erow[c * 128 + X];
                float2 eB = erow[c * 128 + X + 1];
#pragma unroll
                for (int dx = 0; dx < 4; ++dx) {
                    float l = fmaf(eA.x, wA[dx], fmaf(eA.y, wB[dx], eB.y * wC[dx]));
                    acc[dx] += __expf(l);
                }
            }
#pragma unroll
            for (int dx = 0; dx < 4; ++dx) {
                bool valid = (t[dx] != 255);
                int tc = valid ? t[dx] : 0;
                float2 eA = erow[tc * 128 + X];
                float2 eB = erow[tc * 128 + X + 1];
                float lt = fmaf(eA.x, wA[dx], fmaf(eA.y, wB[dx], eB.y * wC[dx]));
                float ls = __logf(acc[dx]);
                float n  = ls - lt;
                float p  = fminf(__expf(-n), 1.0f);
                float pr = valid ? p : 1.0f;        // mask_prob (invalid -> 1.0)
                if (lvl < 3) {
                    unsigned bv = __float_as_uint(pr);
                    if (lvl == 0)      atomicAdd(&ghist[bv >> 18], 1u);
                    else if (lvl == 1) { if ((bv >> 18) == pre) atomicAdd(&ghist[(bv >> 6) & 0xFFFu], 1u); }
                    else               { if ((bv >> 6) == pre) atomicAdd(&ghist[bv & 63u], 1u); }
                } else {
                    if (valid && p <= th) { fs -= __logf(p); ic++; }
                }
            }
            __syncthreads();                       // before next row's erow rewrite
        }

        if (lvl < 3) {
            if (tid == 0) {                        // serial scan (cold path)
                int bins = (lvl == 2) ? 64 : 4096;
                unsigned kr = (lvl == 0) ? 100000u : smu[1];
                unsigned acc = 0;
                for (int idx = 0; idx < bins; ++idx) {
                    unsigned c = ghist[idx];
                    if (acc < kr && kr <= acc + c) {
                        if (lvl == 0)      { smu[0] = (unsigned)idx; smu[1] = kr - acc; }
                        else if (lvl == 1) { smu[0] = (pre << 12) | (unsigned)idx; smu[1] = kr - acc; }
                        else {
                            unsigned bitsv = (pre << 6) | (unsigned)idx;
                            smf[0] = fmaxf(0.7f, __uint_as_float(bitsv));
                        }
                        break;
                    }
                    acc += c;
                }
            }
            __syncthreads();
        } else {
            for (int o = 32; o; o >>= 1) {
                fs += __shfl_down(fs, o, 64);
                ic += (unsigned)__shfl_down((int)ic, o, 64);
            }
            int wave = tid >> 6, lane = tid & 63;
            if (lane == 0) { smf[4 + wave] = fs; smu[4 + wave] = ic; }
            __syncthreads();
            if (tid == 0) {
                smf[1] = smf[4] + smf[5] + smf[6] + smf[7];
                smu[2] = smu[4] + smu[5] + smu[6] + smu[7];
            }
            __syncthreads();
        }
    }
}

// ---------------------------------------------------------------------------
// Single fused kernel, ONE ROW PER BLOCK. Blocks [0,4096) = OHEM: float4
// staging + shfl erow build into the PADDED layout (slot(X)=X+(X>>3), stride
// 144) — thread i's 4 pairs stay slot-contiguous at base 4i+(i>>1) so the
// two b128 writes survive, with bank stride 9 (even spread). px loop math
// verbatim (values bit-identical; only LDS addresses changed). Block-level
// partial store (R5's proven rf-reduce + single tid0 sc1 pair — removes the
// R6 per-wave vmcnt drain). Blocks [4096,4608) = boundary BCE (unchanged).
// Hierarchical completion; last block: decide (R5's exact FP order) ->
// fast combine (verbatim) or cold slow path.
// ---------------------------------------------------------------------------
__global__ __launch_bounds__(256) void fused_all(
    const float* __restrict__ mp, const float* __restrict__ cp,
    const float* __restrict__ bp, const int* __restrict__ seg,
    const float* __restrict__ bg,
    float* __restrict__ ppsum, unsigned* __restrict__ ppcnt,
    float* __restrict__ bps, unsigned* __restrict__ bpc,
    unsigned* __restrict__ cnt1, unsigned* __restrict__ cnt2,
    unsigned* __restrict__ ghist,
    float* __restrict__ out)
{
    __shared__ float2 erow[19 * ESTR];         // 21.9 KB (padded; finisher scratch)
    __shared__ float rf[4]; __shared__ unsigned ru[4];
    __shared__ float rf2[4]; __shared__ unsigned ru2[4];
    __shared__ unsigned amLast;
    __shared__ float Pb[4], Nb[4]; __shared__ unsigned PCb[4], NCb[4];
    __shared__ float smf[8]; __shared__ unsigned smu[8];
    int bk = blockIdx.x;
    int tid = threadIdx.x;

    if (bk < 4096) {
        // Chunked XCD swizzle: XCD (bk&7) gets 512 consecutive tasks.
        int v = ((bk & 7) << 9) | (bk >> 3);
        int head = v >> 11;
        int task = v & 2047;                   // b*512 + y
        int b = task >> 9;
        int y = task & 511;
        const float* pred = head ? cp : mp;

        float fy = (float)y * (63.0f / 511.0f);
        int y0 = min((int)fy, 63);
        int y1 = min(y0 + 1, 63);
        float wy = fy - (float)y0;

        // Prefetch seg early — hides under staging + barrier.
        int xb = tid << 2;
        int P = task * 1024 + xb;              // per-head pixel index
        int4 t4 = *(const int4*)(seg + P);
        int t[4] = {t4.x, t4.y, t4.z, t4.w};

        // Stage + vertical lerp + erow build (float4 loads, shfl neighbor).
        const float* r0 = pred + (size_t)b * IMG_STR + y0 * 128;
        const float* r1 = pred + (size_t)b * IMG_STR + y1 * 128;
#pragma unroll
        for (int sr = 0; sr < 3; ++sr) {
            int s = tid + (sr << 8);           // 608 float4 slots
            float4 cu = make_float4(0.f, 0.f, 0.f, 0.f);
            float4 nx = make_float4(0.f, 0.f, 0.f, 0.f);
            int c = s >> 5, i = s & 31, x4 = i << 2;
            if (s < 608) {
                cu = *(const float4*)(r0 + c * CH_STR + x4);
                nx = *(const float4*)(r1 + c * CH_STR + x4);
            }
            float e0 = fmaf(wy, nx.x - cu.x, cu.x);
            float e1 = fmaf(wy, nx.y - cu.y, cu.y);
            float e2 = fmaf(wy, nx.z - cu.z, cu.z);
            float e3 = fmaf(wy, nx.w - cu.w, cu.w);
            float en = __shfl_down(e0, 1, 64);   // next slot's e0 (same wave)
            if (s < 608) {
                float last = (i == 31) ? e3 : en;  // channel edge pad
                float4 w0 = make_float4(e0, e1, e1, e2);
                float4 w1 = make_float4(e2, e3, e3, last);
                int slot = c * ESTR + x4 + (i >> 1);   // = c*ESTR + idx(x4)
                *(float4*)(&erow[slot])     = w0;      // pairs {x4, x4+1}
                *(float4*)(&erow[slot + 2]) = w1;      // pairs {x4+2, x4+3}
            }
        }
        __syncthreads();

        // Per-thread horizontal taps/weights + padded slots (precomputed once).
        float fx0 = (float)xb * (127.0f / 1023.0f);
        int X = min((int)fx0, 126);                  // taps e[X], e[X+1], e[X+2]
        int slotA = X + (X >> 3);                    // pair X
        int slotB = (X + 1) + ((X + 1) >> 3);        // pair X+1
        float wA[4], wB[4], wC[4];
#pragma unroll
        for (int dx = 0; dx < 4; ++dx) {
            float fx = (float)(xb + dx) * (127.0f / 1023.0f);
            int x0 = min((int)fx, 127);
            float wx = fx - (float)x0;
            bool sm = (x0 == X);
            wA[dx] = sm ? (1.0f - wx) : 0.0f;        // weight on e[X]   (eA.x)
            wB[dx] = sm ? wx : (1.0f - wx);          // weight on e[X+1] (eA.y)
            wC[dx] = sm ? 0.0f : wx;                 // weight on e[X+2] (eB.y)
        }

        // ---- px loop: verbatim hot math (addresses padded, values identical) ----
        float acc[4] = {0.f, 0.f, 0.f, 0.f};
        for (int c = 0; c < 19; ++c) {
            float2 eA = erow[c * ESTR + slotA];      // (e[X],   e[X+1])
            float2 eB = erow[c * ESTR + slotB];      // (e[X+1], e[X+2])
#pragma unroll
            for (int dx = 0; dx < 4; ++dx) {
                float l = fmaf(eA.x, wA[dx], fmaf(eA.y, wB[dx], eB.y * wC[dx]));
                acc[dx] += __expf(l);
            }
        }

        float fs = 0.f; unsigned ic = 0;
#pragma unroll
        for (int dx = 0; dx < 4; ++dx) {
            bool valid = (t[dx] != 255);
            int tc = valid ? t[dx] : 0;
            float2 eA = erow[tc * ESTR + slotA];
            float2 eB = erow[tc * ESTR + slotB];
            float lt = fmaf(eA.x, wA[dx], fmaf(eA.y, wB[dx], eB.y * wC[dx]));  // bit-identical
            float ls = __logf(acc[dx]);
            float n  = ls - lt;                      // nll at target
            float p  = fminf(__expf(-n), 1.0f);
            if (valid && p <= 0.7f) { fs += n; ic++; }
        }

        for (int o = 32; o; o >>= 1) {
            fs += __shfl_down(fs, o, 64);
            ic += (unsigned)__shfl_down((int)ic, o, 64);
        }
        int wave = tid >> 6, lane = tid & 63;
        if (lane == 0) { rf[wave] = fs; ru[wave] = ic; }
        __syncthreads();
        if (tid == 0) {
            st_dev_f(&ppsum[head * 2048 + task], rf[0] + rf[1] + rf[2] + rf[3]);
            st_dev_u(&ppcnt[head * 2048 + task], ru[0] + ru[1] + ru[2] + ru[3]);
        }
    } else {
        // -------- boundary BCE --------
        int bb = bk - 4096;                   // [0,512)
        int b  = bb >> 7;                     // 128 blocks per sample
        int blk = bb & 127;
        float psum = 0.f, nsum = 0.f; unsigned pc = 0, nc = 0;

        for (int g = blk * 256 + tid; g < 131072; g += 128 * 256) {
            int P = g << 2;
            int y = P >> 10, xb = P & 1023;

            float fy = (float)y * (63.0f / 511.0f);
            int y0 = min((int)fy, 63);
            int y1 = min(y0 + 1, 63);
            float wy = fy - (float)y0;

            const float* r0 = bp + b * 8192 + y0 * 128;
            const float* r1 = bp + b * 8192 + y1 * 128;
            float fx0 = (float)xb * (127.0f / 1023.0f);
            int X  = min((int)fx0, 126);
            int X2 = min(X + 2, 127);
            float c0 = r0[X], c1 = r0[X + 1], c2 = r0[X2];
            float d0 = r1[X], d1 = r1[X + 1], d2 = r1[X2];
            float e0 = fmaf(wy, d0 - c0, c0);
            float e1 = fmaf(wy, d1 - c1, c1);
            float e2 = fmaf(wy, d2 - c2, c2);

            float4 t4 = *(const float4*)(bg + (size_t)b * 524288 + P);
            float tv[4] = {t4.x, t4.y, t4.z, t4.w};

#pragma unroll
            for (int dx = 0; dx < 4; ++dx) {
                float fx = (float)(xb + dx) * (127.0f / 1023.0f);
                int x0 = min((int)fx, 127);
                int x1 = min(x0 + 1, 127);
                float wx = fx - (float)x0;
                float a0 = (x0 == X)     ? e0 : e1;
                float a1 = (x1 == X + 1) ? e1 : e2;
                float p  = fmaf(wx, a1 - a0, a0);
                bool isp = (tv[dx] == 1.0f);
                bool isn = (tv[dx] == 0.0f);
                float q = isp ? p : 1.0f - p;
                float l = fmaxf(__logf(q), -100.0f);
                if (isp) { pc++; psum -= l; }
                if (isn) { nc++; nsum -= l; }
            }
        }
        for (int o = 32; o; o >>= 1) {
            psum += __shfl_down(psum, o, 64);
            nsum += __shfl_down(nsum, o, 64);
            pc   += (unsigned)__shfl_down((int)pc, o, 64);
            nc   += (unsigned)__shfl_down((int)nc, o, 64);
        }
        int wave = tid >> 6, lane = tid & 63;
        if (lane == 0) { rf[wave] = psum; rf2[wave] = nsum; ru[wave] = pc; ru2[wave] = nc; }
        __syncthreads();
        if (tid == 0) {
            st_dev_f(&bps[2 * bb],     rf[0] + rf[1] + rf[2] + rf[3]);
            st_dev_f(&bps[2 * bb + 1], rf2[0] + rf2[1] + rf2[2] + rf2[3]);
            st_dev_u(&bpc[2 * bb],     ru[0] + ru[1] + ru[2] + ru[3]);
            st_dev_u(&bpc[2 * bb + 1], ru2[0] + ru2[1] + ru2[2] + ru2[3]);
        }
    }

    // ---------------- last-block finisher ----------------
    // Hierarchical completion: 72 blocks per level-1 bucket (own cacheline),
    // bucket winners (lvl1 old==71) bump level-2; lvl2 old==63 => last block.
    // tid0's sc1 partial stores drained (vmcnt) before its lvl1 add.
    __syncthreads();
    if (tid == 0) {
        asm volatile("s_waitcnt vmcnt(0)" ::: "memory");
        unsigned last = 0u;
        unsigned o1 = __hip_atomic_fetch_add(&cnt1[(bk & 63) << 5], 1u,
                                             __ATOMIC_RELAXED, __HIP_MEMORY_SCOPE_AGENT);
        if (o1 == 71u) {
            unsigned o2 = __hip_atomic_fetch_add(cnt2, 1u,
                                                 __ATOMIC_RELAXED, __HIP_MEMORY_SCOPE_AGENT);
            last = (o2 == 63u) ? 1u : 0u;
        }
        amLast = last;
    }
    __syncthreads();
    if (!amLast) return;

    // ---- decide (identical FP order to the original redundant decide) ----
    float s0 = 0.f, s1 = 0.f; unsigned c0 = 0u, c1 = 0u;
    for (int i = tid; i < 2048; i += 256) {
        s0 += ld_dev_f(&ppsum[i]);        c0 += ld_dev_u(&ppcnt[i]);
        s1 += ld_dev_f(&ppsum[2048 + i]); c1 += ld_dev_u(&ppcnt[2048 + i]);
    }
    for (int o = 32; o; o >>= 1) {
        s0 += __shfl_down(s0, o, 64); s1 += __shfl_down(s1, o, 64);
        c0 += (unsigned)__shfl_down((int)c0, o, 64);
        c1 += (unsigned)__shfl_down((int)c1, o, 64);
    }
    int wv = tid >> 6, ln = tid & 63;
    if (ln == 0) { rf[wv] = s0; rf2[wv] = s1; ru[wv] = c0; ru2[wv] = c1; }
    __syncthreads();
    float S0 = rf[0] + rf[1] + rf[2] + rf[3];
    float S1 = rf2[0] + rf2[1] + rf2[2] + rf2[3];
    unsigned C0 = ru[0] + ru[1] + ru[2] + ru[3];
    unsigned C1 = ru2[0] + ru2[1] + ru2[2] + ru2[3];
    bool done0 = (C0 >= 100000u), done1 = (C1 >= 100000u);

    // Head losses: fast heads verbatim; undone heads via cold recompute.
    float hl0, hl1;
    if (done0) {
        hl0 = S0 / fmaxf((float)C0, 1.f);
    } else {
        slow_head(tid, mp, seg, ghist, erow, smf, smu);
        hl0 = smf[1] / fmaxf((float)smu[2], 1.f);
    }
    if (done1) {
        hl1 = S1 / fmaxf((float)C1, 1.f);
    } else {
        slow_head(tid, cp, seg, ghist, erow, smf, smu);
        hl1 = smf[1] / fmaxf((float)smu[2], 1.f);
    }
    float hls = hl0 + hl1;

    // boundary combine — same tree algorithm/order as before (absmax-proven)
    {
        float*    lf = (float*)erow;
        unsigned* lu = (unsigned*)erow + 256;
        for (int b = 0; b < 4; ++b) {
            float ps = 0.f, ns = 0.f; unsigned p_c = 0, n_c = 0;
            if (tid < 128) {
                int jj = b * 128 + tid;
                ps  = ld_dev_f(&bps[2 * jj]); ns  = ld_dev_f(&bps[2 * jj + 1]);
                p_c = ld_dev_u(&bpc[2 * jj]); n_c = ld_dev_u(&bpc[2 * jj + 1]);
            }
            lf[tid] = ps; lu[tid] = p_c; __syncthreads();
            for (int o = 128; o; o >>= 1) {
                if (tid < o) { lf[tid] += lf[tid + o]; lu[tid] += lu[tid + o]; }
                __syncthreads();
            }
            if (tid == 0) { Pb[b] = lf[0]; PCb[b] = lu[0]; }
            __syncthreads();
            lf[tid] = ns; lu[tid] = n_c; __syncthreads();
            for (int o = 128; o; o >>= 1) {
                if (tid < o) { lf[tid] += lf[tid + o]; lu[tid] += lu[tid + o]; }
                __syncthreads();
            }
            if (tid == 0) { Nb[b] = lf[0]; NCb[b] = lu[0]; }
            __syncthreads();
        }
        if (tid == 0) {
            float bt = 0.f;
            for (int b = 0; b < 4; ++b) {
                float pos = (float)PCb[b], neg = (float)NCb[b];
                float val = fmaxf(pos + neg, 1.f);
                bt += (neg / val) * Pb[b] + (pos / val) * Nb[b];
            }
            out[0] = hls + bt / 2097152.0f;
        }
    }
}

extern "C" void kernel_launch(void* const* d_in, const int* in_sizes, int n_in,
                              void* d_out, int out_size, void* d_ws, size_t ws_size,
                              hipStream_t stream)
{
    const float* mp  = (const float*)d_in[0];
    const float* cp  = (const float*)d_in[1];
    const float* bp  = (const float*)d_in[2];
    const int*   seg = (const int*)d_in[3];
    const float* bg  = (const float*)d_in[4];
    float* out = (float*)d_out;

    char* ws = (char*)d_ws;
    unsigned* ctl    = (unsigned*)(ws + OFF_CTL);
    unsigned* cnt1   = ctl + CTL_CNT1;
    unsigned* cnt2   = ctl + CTL_CNT2;
    unsigned* ghist  = ctl + CTL_GHIST;
    float*    ppsum  = (float*)(ctl + CTL_PPSUM);
    unsigned* ppcnt  = ctl + CTL_PPCNT;
    float*    bps    = (float*)(ctl + CTL_BPS);
    unsigned* bpc    = ctl + CTL_BPC;

    // Zero completion counters only (ghist is zeroed by the slow path itself).
    hipMemsetAsync(ws + OFF_CTL, 0, 2052ull * 4, stream);

    fused_all<<<dim3(GRID_P1), 256, 0, stream>>>(mp, cp, bp, seg, bg,
                                                 ppsum, ppcnt, bps, bpc,
                                                 cnt1, cnt2, ghist, out);
}